// Round 3
// baseline (105.314 us; speedup 1.0000x reference)
//
#include <hip/hip_runtime.h>
#include <hip/hip_bf16.h>

typedef __bf16 bf16x8 __attribute__((ext_vector_type(8)));
typedef __bf16 bf16x4 __attribute__((ext_vector_type(4)));
typedef float  f32x4  __attribute__((ext_vector_type(4)));

#define HF 128          // hidden dim
#define W1K 256         // W1 inner dim (2H)

// ================= Kernel 1: per-node linear precompute (v2) =================
// u[n][c] = A . x_src[n] + b1,  v[n][c] = B . x_dst[n]   (W1 = [A | B])
// MFMA with W as A-operand (M=channels), nodes as B-operand (N).
// D layout: col(l15)=node, row(lg*4+r)=channel -> 4 consecutive channels/lane
// -> ushort4 packed stores.
__global__ __launch_bounds__(256, 4) void node_precompute2(
    const float* __restrict__ x_src, const float* __restrict__ x_dst,
    const float* __restrict__ W1, const float* __restrict__ b1,
    __bf16* __restrict__ u, __bf16* __restrict__ v, int nNodes)
{
    __shared__ __align__(16) __bf16 wlds[32 * 64 * 8];   // 32 KiB

    const int which = blockIdx.y;                 // 0 -> u/A, 1 -> v/B
    const float* __restrict__ x = which ? x_dst : x_src;
    const float* __restrict__ W = W1 + (which ? HF : 0);
    __bf16* __restrict__ outp = which ? v : u;

    const int tid  = threadIdx.x;
    const int lane = tid & 63;
    const int wid  = tid >> 6;
    const int l15  = lane & 15;
    const int lg   = lane >> 4;

    // stage W (128x128 fp32, row stride 256) -> bf16 LDS, A-fragment order
    // frag p = mt*4 + kk : channel row = mt*16 + l15, k = kk*32 + lg*8
    for (int p = wid; p < 32; p += 4) {
        const int mt = p >> 2;
        const int kk = p & 3;
        const float* srcp = W + (mt * 16 + l15) * W1K + kk * 32 + lg * 8;
        bf16x8 w8;
        #pragma unroll
        for (int i = 0; i < 8; ++i) w8[i] = (__bf16)srcp[i];
        *reinterpret_cast<bf16x8*>(&wlds[(p * 64 + lane) * 8]) = w8;
    }
    __syncthreads();

    // each wave: one 16-node N-tile, all 8 channel M-tiles
    const int nbase = (blockIdx.x * 4 + wid) * 16;
    int node = nbase + l15;
    const int nodec = min(node, nNodes - 1);      // clamped for loads
    const float* rowp = x + (size_t)nodec * HF + lg * 8;

    f32x4 acc[8];
    #pragma unroll
    for (int mt = 0; mt < 8; ++mt) acc[mt] = (f32x4){0.f, 0.f, 0.f, 0.f};

    #pragma unroll
    for (int kk = 0; kk < 4; ++kk) {
        f32x4 u0 = *reinterpret_cast<const f32x4*>(rowp + kk * 32);
        f32x4 u1 = *reinterpret_cast<const f32x4*>(rowp + kk * 32 + 4);
        bf16x8 xb;
        #pragma unroll
        for (int i = 0; i < 4; ++i) {
            xb[i]     = (__bf16)u0[i];
            xb[i + 4] = (__bf16)u1[i];
        }
        #pragma unroll
        for (int mt = 0; mt < 8; ++mt) {
            bf16x8 wa = *reinterpret_cast<const bf16x8*>(
                &wlds[((mt * 4 + kk) * 64 + lane) * 8]);
            acc[mt] = __builtin_amdgcn_mfma_f32_16x16x32_bf16(
                wa, xb, acc[mt], 0, 0, 0);
        }
    }

    // epilogue: channel = mt*16 + lg*4 + r for node (col l15)
    const int mynode = nbase + l15;
    if (mynode < nNodes) {
        __bf16* op = outp + (size_t)mynode * HF + lg * 4;
        #pragma unroll
        for (int mt = 0; mt < 8; ++mt) {
            f32x4 b4 = {0.f, 0.f, 0.f, 0.f};
            if (which == 0)
                b4 = *reinterpret_cast<const f32x4*>(b1 + mt * 16 + lg * 4);
            bf16x4 o4;
            #pragma unroll
            for (int r = 0; r < 4; ++r)
                o4[r] = (__bf16)(acc[mt][r] + b4[r]);
            *reinterpret_cast<bf16x4*>(op + mt * 16) = o4;
        }
    }
}

// ================= Kernel 2: per-edge score (pure gather) =================
// score[e] = W2 . relu(u[src[e]] + v[dst[e]]) + b2
// 16 lanes per edge, 8 channels (16 B bf16) per lane, 4 edges per subgroup.
__global__ __launch_bounds__(256) void edge_score_kernel(
    const __bf16* __restrict__ u, const __bf16* __restrict__ v,
    const int* __restrict__ sidx, const int* __restrict__ didx,
    const float* __restrict__ W2, const float* __restrict__ b2,
    float* __restrict__ out, int nEdges)
{
    const int tid = threadIdx.x;
    const int sub = tid >> 4;        // 0..15
    const int l16 = tid & 15;

    const int ebase = blockIdx.x * 64 + sub;   // edges ebase + {0,16,32,48}

    float w2v[8];
    #pragma unroll
    for (int j = 0; j < 8; ++j) w2v[j] = W2[l16 * 8 + j];
    const float b2v = b2[0];

    int e[4], si[4], di[4];
    #pragma unroll
    for (int q = 0; q < 4; ++q) {
        e[q] = ebase + q * 16;
        const int c = min(e[q], nEdges - 1);
        si[q] = sidx[c];
        di[q] = didx[c];
    }

    bf16x8 uv[4], vv[4];
    #pragma unroll
    for (int q = 0; q < 4; ++q) {
        uv[q] = *reinterpret_cast<const bf16x8*>(u + (size_t)si[q] * HF + l16 * 8);
        vv[q] = *reinterpret_cast<const bf16x8*>(v + (size_t)di[q] * HF + l16 * 8);
    }

    float s[4] = {0.f, 0.f, 0.f, 0.f};
    #pragma unroll
    for (int q = 0; q < 4; ++q)
        #pragma unroll
        for (int j = 0; j < 8; ++j)
            s[q] += fmaxf((float)uv[q][j] + (float)vv[q][j], 0.f) * w2v[j];

    #pragma unroll
    for (int off = 1; off < 16; off <<= 1)
        #pragma unroll
        for (int q = 0; q < 4; ++q)
            s[q] += __shfl_xor(s[q], off, 64);

    if (l16 == 0) {
        #pragma unroll
        for (int q = 0; q < 4; ++q)
            if (e[q] < nEdges) out[e[q]] = s[q] + b2v;
    }
}

// ================= Fallback: fused single kernel (round-1) =================
__global__ __launch_bounds__(256, 2) void edge_mlp_kernel(
    const float* __restrict__ x_src, const float* __restrict__ x_dst,
    const int*   __restrict__ src_idx, const int* __restrict__ dst_idx,
    const float* __restrict__ W1, const float* __restrict__ b1,
    const float* __restrict__ W2, const float* __restrict__ b2,
    float* __restrict__ out, int nEdges)
{
    __shared__ __align__(16) __bf16 w1lds[64 * 64 * 8];

    const int tid  = threadIdx.x;
    const int lane = tid & 63;
    const int wid  = tid >> 6;
    const int l15  = lane & 15;
    const int lg   = lane >> 4;

    for (int p = wid; p < 64; p += 4) {
        const int n   = p >> 3;
        const int kk  = p & 7;
        const float* src = W1 + (n * 16 + l15) * W1K + kk * 32 + lg * 8;
        bf16x8 w8;
        #pragma unroll
        for (int i = 0; i < 8; ++i) w8[i] = (__bf16)src[i];
        *reinterpret_cast<bf16x8*>(&w1lds[(p * 64 + lane) * 8]) = w8;
    }
    __syncthreads();

    float w2v[8], b1v[8];
    #pragma unroll
    for (int n = 0; n < 8; ++n) {
        w2v[n] = W2[n * 16 + l15];
        b1v[n] = b1[n * 16 + l15];
    }
    const float b2v = b2[0];

    const int ntiles = nEdges / 256;
    for (int t = blockIdx.x; t < ntiles; t += gridDim.x) {
        const int ebase = t * 256 + wid * 64;

        const float* srow[4];
        const float* drow[4];
        #pragma unroll
        for (int m = 0; m < 4; ++m) {
            const int e  = ebase + m * 16 + l15;
            srow[m] = x_src + (size_t)src_idx[e] * HF + lg * 8;
            drow[m] = x_dst + (size_t)dst_idx[e] * HF + lg * 8;
        }

        f32x4 acc[4][8];
        #pragma unroll
        for (int m = 0; m < 4; ++m)
            #pragma unroll
            for (int n = 0; n < 8; ++n)
                acc[m][n] = (f32x4){0.f, 0.f, 0.f, 0.f};

        #pragma unroll
        for (int kk = 0; kk < 8; ++kk) {
            bf16x8 a[4];
            #pragma unroll
            for (int m = 0; m < 4; ++m) {
                const float* p = (kk < 4) ? (srow[m] + kk * 32)
                                          : (drow[m] + (kk - 4) * 32);
                f32x4 u0 = *reinterpret_cast<const f32x4*>(p);
                f32x4 u1 = *reinterpret_cast<const f32x4*>(p + 4);
                bf16x8 av;
                #pragma unroll
                for (int i = 0; i < 4; ++i) {
                    av[i]     = (__bf16)u0[i];
                    av[i + 4] = (__bf16)u1[i];
                }
                a[m] = av;
            }
            #pragma unroll
            for (int n = 0; n < 8; ++n) {
                bf16x8 bfrag = *reinterpret_cast<const bf16x8*>(
                    &w1lds[((n * 8 + kk) * 64 + lane) * 8]);
                #pragma unroll
                for (int m = 0; m < 4; ++m) {
                    acc[m][n] = __builtin_amdgcn_mfma_f32_16x16x32_bf16(
                        a[m], bfrag, acc[m][n], 0, 0, 0);
                }
            }
        }

        #pragma unroll
        for (int m = 0; m < 4; ++m) {
            float part[4];
            #pragma unroll
            for (int r = 0; r < 4; ++r) {
                float s = 0.f;
                #pragma unroll
                for (int n = 0; n < 8; ++n) {
                    float hv = acc[m][n][r] + b1v[n];
                    s += fmaxf(hv, 0.f) * w2v[n];
                }
                part[r] = s;
            }
            #pragma unroll
            for (int off = 1; off < 16; off <<= 1) {
                #pragma unroll
                for (int r = 0; r < 4; ++r)
                    part[r] += __shfl_xor(part[r], off, 64);
            }
            if (l15 == m) {
                f32x4 v4 = { part[0] + b2v, part[1] + b2v,
                             part[2] + b2v, part[3] + b2v };
                *reinterpret_cast<f32x4*>(&out[ebase + m * 16 + lg * 4]) = v4;
            }
        }
    }
}

extern "C" void kernel_launch(void* const* d_in, const int* in_sizes, int n_in,
                              void* d_out, int out_size, void* d_ws, size_t ws_size,
                              hipStream_t stream) {
    const float* x_src  = (const float*)d_in[0];
    const float* x_dst  = (const float*)d_in[1];
    const int*   sidx   = (const int*)d_in[2];
    const int*   didx   = (const int*)d_in[3];
    const float* W1     = (const float*)d_in[4];
    const float* b1     = (const float*)d_in[5];
    const float* W2     = (const float*)d_in[6];
    const float* b2     = (const float*)d_in[7];
    float* out = (float*)d_out;

    const int nEdges = in_sizes[2];
    const int nNodes = in_sizes[0] / HF;

    const size_t needed = (size_t)2 * nNodes * HF * sizeof(__bf16);  // u + v
    if (ws_size >= needed) {
        __bf16* u = (__bf16*)d_ws;
        __bf16* v = u + (size_t)nNodes * HF;

        dim3 pgrid((nNodes + 63) / 64, 2);
        node_precompute2<<<pgrid, 256, 0, stream>>>(
            x_src, x_dst, W1, b1, u, v, nNodes);

        const int egrid = (nEdges + 63) / 64;
        edge_score_kernel<<<egrid, 256, 0, stream>>>(
            u, v, sidx, didx, W2, b2, out, nEdges);
    } else {
        edge_mlp_kernel<<<512, 256, 0, stream>>>(
            x_src, x_dst, sidx, didx, W1, b1, W2, b2, out, nEdges);
    }
}

// Round 4
// 86.345 us; speedup vs baseline: 1.2197x; 1.2197x over previous
//
#include <hip/hip_runtime.h>
#include <hip/hip_bf16.h>

typedef __bf16 bf16x8 __attribute__((ext_vector_type(8)));
typedef __bf16 bf16x4 __attribute__((ext_vector_type(4)));
typedef float  f32x4  __attribute__((ext_vector_type(4)));

#define HF 128          // hidden dim
#define W1K 256         // W1 inner dim (2H)

// ============ Kernel 1: per-node linear precompute (v3, reg-resident W) ====
// u[n] = A . x_src[n],  v[n] = B . x_dst[n]    (W1 = [A | B]; b1 moved to k2)
// Each wave: loads its half's 32 A-fragments into 128 VGPRs ONCE, then
// grid-strides over 16-node subtiles: 8 prefetched f32x4 loads + 32 MFMA.
// No LDS, no barriers. D layout: col(l15)=node, row(lg*4+r)=channel.
__global__ __launch_bounds__(256, 2) void node_precompute3(
    const float* __restrict__ x_src, const float* __restrict__ x_dst,
    const float* __restrict__ W1,
    __bf16* __restrict__ u, __bf16* __restrict__ v, int nNodes)
{
    const int tid  = threadIdx.x;
    const int lane = tid & 63;
    const int wid  = tid >> 6;
    const int l15  = lane & 15;
    const int lg   = lane >> 4;

    const int gw     = blockIdx.x * 4 + wid;       // global wave id
    const int half   = gw & 1;                     // 0 -> u/A, 1 -> v/B
    const int stride = gridDim.x * 2;              // waves per half

    const float* __restrict__ x = half ? x_dst : x_src;
    const float* __restrict__ Wh = W1 + (half ? HF : 0);
    __bf16* __restrict__ outp = half ? v : u;

    // ---- one-time: load 32 W fragments into registers ----
    // frag f = mt*4 + kk : A[row = mt*16 + l15][k = kk*32 + lg*8 .. +8]
    bf16x8 wfrag[32];
    #pragma unroll
    for (int f = 0; f < 32; ++f) {
        const int mt = f >> 2;
        const int kk = f & 3;
        const float* p = Wh + (size_t)(mt * 16 + l15) * W1K + kk * 32 + lg * 8;
        f32x4 a = *reinterpret_cast<const f32x4*>(p);
        f32x4 b = *reinterpret_cast<const f32x4*>(p + 4);
        bf16x8 w8;
        #pragma unroll
        for (int i = 0; i < 4; ++i) {
            w8[i]     = (__bf16)a[i];
            w8[i + 4] = (__bf16)b[i];
        }
        wfrag[f] = w8;
    }

    const int nst = (nNodes + 15) >> 4;            // 6250 subtiles per half
    const size_t laneoff = (size_t)l15 * HF + lg * 8;

    int st = gw >> 1;
    if (st >= nst) return;

    // prefetch first subtile
    f32x4 nxt[8];
    {
        const int node = min(st * 16 + l15, nNodes - 1);
        const float* rp = x + (size_t)node * HF + lg * 8;
        #pragma unroll
        for (int kk = 0; kk < 4; ++kk) {
            nxt[2 * kk]     = *reinterpret_cast<const f32x4*>(rp + kk * 32);
            nxt[2 * kk + 1] = *reinterpret_cast<const f32x4*>(rp + kk * 32 + 4);
        }
    }

    while (st < nst) {
        const int st2 = st + stride;

        // pack current x into bf16 B-fragments (frees nxt for next prefetch)
        bf16x8 xb[4];
        #pragma unroll
        for (int kk = 0; kk < 4; ++kk) {
            bf16x8 t;
            #pragma unroll
            for (int i = 0; i < 4; ++i) {
                t[i]     = (__bf16)nxt[2 * kk][i];
                t[i + 4] = (__bf16)nxt[2 * kk + 1][i];
            }
            xb[kk] = t;
        }

        // prefetch next subtile (latency hidden under MFMAs below)
        if (st2 < nst) {
            const int node = min(st2 * 16 + l15, nNodes - 1);
            const float* rp = x + (size_t)node * HF + lg * 8;
            #pragma unroll
            for (int kk = 0; kk < 4; ++kk) {
                nxt[2 * kk]     = *reinterpret_cast<const f32x4*>(rp + kk * 32);
                nxt[2 * kk + 1] = *reinterpret_cast<const f32x4*>(rp + kk * 32 + 4);
            }
        }

        f32x4 acc[8];
        #pragma unroll
        for (int mt = 0; mt < 8; ++mt) acc[mt] = (f32x4){0.f, 0.f, 0.f, 0.f};

        #pragma unroll
        for (int kk = 0; kk < 4; ++kk)
            #pragma unroll
            for (int mt = 0; mt < 8; ++mt)
                acc[mt] = __builtin_amdgcn_mfma_f32_16x16x32_bf16(
                    wfrag[mt * 4 + kk], xb[kk], acc[mt], 0, 0, 0);

        // store: node = st*16 + l15, channels mt*16 + lg*4 .. +4
        const int mynode = st * 16 + l15;
        if (mynode < nNodes) {
            __bf16* op = outp + (size_t)mynode * HF + lg * 4;
            #pragma unroll
            for (int mt = 0; mt < 8; ++mt) {
                bf16x4 o4;
                #pragma unroll
                for (int r = 0; r < 4; ++r) o4[r] = (__bf16)acc[mt][r];
                *reinterpret_cast<bf16x4*>(op + mt * 16) = o4;
            }
        }
        st = st2;
    }
}

// ================= Kernel 2: per-edge score (pure gather) =================
// score[e] = W2 . relu(u[src[e]] + v[dst[e]] + b1) + b2
// 16 lanes per edge, 8 channels (16 B bf16) per lane, 4 edges per subgroup.
__global__ __launch_bounds__(256) void edge_score_kernel(
    const __bf16* __restrict__ u, const __bf16* __restrict__ v,
    const int* __restrict__ sidx, const int* __restrict__ didx,
    const float* __restrict__ W2, const float* __restrict__ b1,
    const float* __restrict__ b2,
    float* __restrict__ out, int nEdges)
{
    const int tid = threadIdx.x;
    const int sub = tid >> 4;        // 0..15
    const int l16 = tid & 15;

    const int ebase = blockIdx.x * 64 + sub;   // edges ebase + {0,16,32,48}

    float w2v[8], b1v[8];
    #pragma unroll
    for (int j = 0; j < 8; ++j) {
        w2v[j] = W2[l16 * 8 + j];
        b1v[j] = b1[l16 * 8 + j];
    }
    const float b2v = b2[0];

    int e[4], si[4], di[4];
    #pragma unroll
    for (int q = 0; q < 4; ++q) {
        e[q] = ebase + q * 16;
        const int c = min(e[q], nEdges - 1);
        si[q] = sidx[c];
        di[q] = didx[c];
    }

    bf16x8 uv[4], vv[4];
    #pragma unroll
    for (int q = 0; q < 4; ++q) {
        uv[q] = *reinterpret_cast<const bf16x8*>(u + (size_t)si[q] * HF + l16 * 8);
        vv[q] = *reinterpret_cast<const bf16x8*>(v + (size_t)di[q] * HF + l16 * 8);
    }

    float s[4] = {0.f, 0.f, 0.f, 0.f};
    #pragma unroll
    for (int q = 0; q < 4; ++q)
        #pragma unroll
        for (int j = 0; j < 8; ++j)
            s[q] += fmaxf((float)uv[q][j] + (float)vv[q][j] + b1v[j], 0.f) * w2v[j];

    #pragma unroll
    for (int off = 1; off < 16; off <<= 1)
        #pragma unroll
        for (int q = 0; q < 4; ++q)
            s[q] += __shfl_xor(s[q], off, 64);

    if (l16 == 0) {
        #pragma unroll
        for (int q = 0; q < 4; ++q)
            if (e[q] < nEdges) out[e[q]] = s[q] + b2v;
    }
}

// ================= Fallback: fused single kernel (round-1) =================
__global__ __launch_bounds__(256, 2) void edge_mlp_kernel(
    const float* __restrict__ x_src, const float* __restrict__ x_dst,
    const int*   __restrict__ src_idx, const int* __restrict__ dst_idx,
    const float* __restrict__ W1, const float* __restrict__ b1,
    const float* __restrict__ W2, const float* __restrict__ b2,
    float* __restrict__ out, int nEdges)
{
    __shared__ __align__(16) __bf16 w1lds[64 * 64 * 8];

    const int tid  = threadIdx.x;
    const int lane = tid & 63;
    const int wid  = tid >> 6;
    const int l15  = lane & 15;
    const int lg   = lane >> 4;

    for (int p = wid; p < 64; p += 4) {
        const int n   = p >> 3;
        const int kk  = p & 7;
        const float* src = W1 + (n * 16 + l15) * W1K + kk * 32 + lg * 8;
        bf16x8 w8;
        #pragma unroll
        for (int i = 0; i < 8; ++i) w8[i] = (__bf16)src[i];
        *reinterpret_cast<bf16x8*>(&w1lds[(p * 64 + lane) * 8]) = w8;
    }
    __syncthreads();

    float w2v[8], b1v[8];
    #pragma unroll
    for (int n = 0; n < 8; ++n) {
        w2v[n] = W2[n * 16 + l15];
        b1v[n] = b1[n * 16 + l15];
    }
    const float b2v = b2[0];

    const int ntiles = nEdges / 256;
    for (int t = blockIdx.x; t < ntiles; t += gridDim.x) {
        const int ebase = t * 256 + wid * 64;

        const float* srow[4];
        const float* drow[4];
        #pragma unroll
        for (int m = 0; m < 4; ++m) {
            const int e  = ebase + m * 16 + l15;
            srow[m] = x_src + (size_t)src_idx[e] * HF + lg * 8;
            drow[m] = x_dst + (size_t)dst_idx[e] * HF + lg * 8;
        }

        f32x4 acc[4][8];
        #pragma unroll
        for (int m = 0; m < 4; ++m)
            #pragma unroll
            for (int n = 0; n < 8; ++n)
                acc[m][n] = (f32x4){0.f, 0.f, 0.f, 0.f};

        #pragma unroll
        for (int kk = 0; kk < 8; ++kk) {
            bf16x8 a[4];
            #pragma unroll
            for (int m = 0; m < 4; ++m) {
                const float* p = (kk < 4) ? (srow[m] + kk * 32)
                                          : (drow[m] + (kk - 4) * 32);
                f32x4 u0 = *reinterpret_cast<const f32x4*>(p);
                f32x4 u1 = *reinterpret_cast<const f32x4*>(p + 4);
                bf16x8 av;
                #pragma unroll
                for (int i = 0; i < 4; ++i) {
                    av[i]     = (__bf16)u0[i];
                    av[i + 4] = (__bf16)u1[i];
                }
                a[m] = av;
            }
            #pragma unroll
            for (int n = 0; n < 8; ++n) {
                bf16x8 bfrag = *reinterpret_cast<const bf16x8*>(
                    &w1lds[((n * 8 + kk) * 64 + lane) * 8]);
                #pragma unroll
                for (int m = 0; m < 4; ++m) {
                    acc[m][n] = __builtin_amdgcn_mfma_f32_16x16x32_bf16(
                        a[m], bfrag, acc[m][n], 0, 0, 0);
                }
            }
        }

        #pragma unroll
        for (int m = 0; m < 4; ++m) {
            float part[4];
            #pragma unroll
            for (int r = 0; r < 4; ++r) {
                float s = 0.f;
                #pragma unroll
                for (int n = 0; n < 8; ++n) {
                    float hv = acc[m][n][r] + b1v[n];
                    s += fmaxf(hv, 0.f) * w2v[n];
                }
                part[r] = s;
            }
            #pragma unroll
            for (int off = 1; off < 16; off <<= 1) {
                #pragma unroll
                for (int r = 0; r < 4; ++r)
                    part[r] += __shfl_xor(part[r], off, 64);
            }
            if (l15 == m) {
                f32x4 v4 = { part[0] + b2v, part[1] + b2v,
                             part[2] + b2v, part[3] + b2v };
                *reinterpret_cast<f32x4*>(&out[ebase + m * 16 + lg * 4]) = v4;
            }
        }
    }
}

extern "C" void kernel_launch(void* const* d_in, const int* in_sizes, int n_in,
                              void* d_out, int out_size, void* d_ws, size_t ws_size,
                              hipStream_t stream) {
    const float* x_src  = (const float*)d_in[0];
    const float* x_dst  = (const float*)d_in[1];
    const int*   sidx   = (const int*)d_in[2];
    const int*   didx   = (const int*)d_in[3];
    const float* W1     = (const float*)d_in[4];
    const float* b1     = (const float*)d_in[5];
    const float* W2     = (const float*)d_in[6];
    const float* b2     = (const float*)d_in[7];
    float* out = (float*)d_out;

    const int nEdges = in_sizes[2];
    const int nNodes = in_sizes[0] / HF;

    const size_t needed = (size_t)2 * nNodes * HF * sizeof(__bf16);  // u + v
    if (ws_size >= needed) {
        __bf16* u = (__bf16*)d_ws;
        __bf16* v = u + (size_t)nNodes * HF;

        node_precompute3<<<512, 256, 0, stream>>>(
            x_src, x_dst, W1, u, v, nNodes);

        const int egrid = (nEdges + 63) / 64;
        edge_score_kernel<<<egrid, 256, 0, stream>>>(
            u, v, sidx, didx, W2, b1, b2, out, nEdges);
    } else {
        edge_mlp_kernel<<<512, 256, 0, stream>>>(
            x_src, x_dst, sidx, didx, W1, b1, W2, b2, out, nEdges);
    }
}